// Round 7
// baseline (262.972 us; speedup 1.0000x reference)
//
#include <hip/hip_runtime.h>
#include <stdint.h>

#define NROWS 16384
#define DIM 512
#define CSPLIT 8
#define COLS_PER_SPLIT (NROWS / CSPLIT)   // 2048
#define BM 256                            // rows per block (4 waves x 64)
#define NT 32                             // cols per tile
#define BK 64                             // k per K-step (= one MFMA K)
#define NTILES (COLS_PER_SPLIT / NT)      // 64
#define PPT (DIM / BK)                    // 8 K-steps per tile
#define NPHASE (NTILES * PPT)             // 512

using i32x4 = __attribute__((ext_vector_type(4))) int;
using char8 = __attribute__((ext_vector_type(8))) signed char;

#define AS1 __attribute__((address_space(1)))
#define AS3 __attribute__((address_space(3)))

// ---------------- Kernel A: L2-normalize + per-row i8 quantize --------------
__global__ __launch_bounds__(256) void knorm(const float* __restrict__ in,
                                             signed char* __restrict__ xq,
                                             float* __restrict__ inv,
                                             float* __restrict__ scl) {
  const int lane = threadIdx.x & 63;
  const int wave = threadIdx.x >> 6;
  const int row = blockIdx.x * 4 + wave;
  const float4* p = (const float4*)(in + (size_t)row * DIM + lane * 8);
  const float4 a = p[0], b = p[1];
  float ss = a.x*a.x + a.y*a.y + a.z*a.z + a.w*a.w
           + b.x*b.x + b.y*b.y + b.z*b.z + b.w*b.w;
  float am = fmaxf(fmaxf(fmaxf(fabsf(a.x), fabsf(a.y)), fmaxf(fabsf(a.z), fabsf(a.w))),
                   fmaxf(fmaxf(fabsf(b.x), fabsf(b.y)), fmaxf(fabsf(b.z), fabsf(b.w))));
  #pragma unroll
  for (int m = 32; m >= 1; m >>= 1) {
    ss += __shfl_xor(ss, m, 64);
    am = fmaxf(am, __shfl_xor(am, m, 64));
  }
  const float iv = 1.0f / fmaxf(sqrtf(ss), 1e-8f);
  const float r127 = 127.0f / am;
  char8 q;
  q[0] = (signed char)(int)rintf(a.x * r127);
  q[1] = (signed char)(int)rintf(a.y * r127);
  q[2] = (signed char)(int)rintf(a.z * r127);
  q[3] = (signed char)(int)rintf(a.w * r127);
  q[4] = (signed char)(int)rintf(b.x * r127);
  q[5] = (signed char)(int)rintf(b.y * r127);
  q[6] = (signed char)(int)rintf(b.z * r127);
  q[7] = (signed char)(int)rintf(b.w * r127);
  *(char8*)(xq + (size_t)row * DIM + lane * 8) = q;
  if (lane == 0) {
    inv[row] = iv;
    scl[row] = am * iv * (1.0f / 127.0f);
  }
}

// ---------------- Kernel B: i8 Gram + fused argmax, BARRIER-FREE main loop --
// 4 waves x 64 rows; A register-resident (128 VGPR). Each wave owns a private
// set of 4 x 2 KB LDS buffers (32c x 64k tiles) and runs its own pipeline:
// depth-3 global_load_lds staging, per-wave counted vmcnt(4), B-frags
// software-pipelined one K-step ahead in regs. NO block barriers in the loop;
// waves drift so epilogue VALU / load latency of one wave is covered by the
// others' MFMAs. 8 independent MFMAs per K-step (4 rf x 2 cf, K=64 whole).
__global__ __launch_bounds__(256, 2) void kdots(const signed char* __restrict__ xq,
                                                const float* __restrict__ scl,
                                                uint32_t* __restrict__ keys) {
  const int tid  = threadIdx.x;
  const int lane = tid & 63;
  const int wave = tid >> 6;
  const int bx = blockIdx.x;
  const int cs = bx & (CSPLIT - 1);     // same-cs blocks land on same XCD (%8)
  const int rb = bx >> 3;
  const int rowbase  = rb * BM + wave * 64;
  const int colsplit = cs * COLS_PER_SPLIT;
  // the two 32-col tiles (per wave) that can contain diagonal elements
  const int td = ((rowbase >> 11) == cs) ? ((rowbase - colsplit) >> 5) : -3;

  __shared__ signed char lds[4][4][NT * BK];   // [wave][buf][2 KB] = 32 KB
  __shared__ float sscl[COLS_PER_SPLIT];       // 8 KB

  // stage this slice's column scales into LDS (read in epilogue only)
  {
    const float4* sp = (const float4*)(scl + colsplit + tid * 8);
    float4* dp = (float4*)(sscl + tid * 8);
    dp[0] = sp[0];
    dp[1] = sp[1];
  }

  // ---- A fragments in registers: 4 rowfrags x 8 kfrags(K=64) = 128 VGPR ----
  i32x4 areg[4][8];
  #pragma unroll
  for (int rf = 0; rf < 4; ++rf) {
    const signed char* ap =
        xq + (size_t)(rowbase + rf * 16 + (lane & 15)) * DIM + ((lane >> 4) * 16);
    #pragma unroll
    for (int kf = 0; kf < 8; ++kf)
      areg[rf][kf] = *(const i32x4*)(ap + kf * 64);
  }

  uint32_t rkey[4][4];
  #pragma unroll
  for (int rf = 0; rf < 4; ++rf)
    #pragma unroll
    for (int r = 0; r < 4; ++r) rkey[rf][r] = 0u;

  char* const ldsW = (char*)&lds[wave][0][0];
  // per-lane constant pieces of the ds_read address: [cf][kslot][col][16B]
  const int rdoff = (lane >> 4) * 256 + (lane & 15) * 16;

  // stage one 2 KB buffer (32 cols x 64 k): 2 global_load_lds(16B) per lane
  auto STAGE = [&](int buf, int p) {
    const int tt = p >> 3, kb2 = p & 7;
    const signed char* gb =
        xq + (size_t)(colsplit + tt * NT) * DIM + kb2 * BK + (lane >> 4) * 16;
    char* lb = ldsW + buf * 2048 + lane * 16;
    #pragma unroll
    for (int i = 0; i < 2; ++i) {
      const signed char* g = gb + (size_t)(i * 16 + (lane & 15)) * DIM;
      __builtin_amdgcn_global_load_lds((AS1 const void*)g,
                                       (AS3 void*)(lb + i * 1024), 16, 0, 0);
    }
  };

  __syncthreads();   // sscl visible; drains areg loads (vmcnt -> 0)
  STAGE(0, 0); STAGE(1, 1); STAGE(2, 2);        // depth-3 prologue: 6 out
  asm volatile("s_waitcnt vmcnt(4)" ::: "memory");   // buf0 landed
  i32x4 fc0 = *(const i32x4*)(ldsW + rdoff);
  i32x4 fc1 = *(const i32x4*)(ldsW + 1024 + rdoff);

  for (int t = 0; t < NTILES; ++t) {
    i32x4 acc[4][2];
    #pragma unroll
    for (int rf = 0; rf < 4; ++rf) {
      acc[rf][0] = (i32x4){0, 0, 0, 0};
      acc[rf][1] = (i32x4){0, 0, 0, 0};
    }

    #pragma unroll
    for (int kb = 0; kb < PPT; ++kb) {
      const int s = t * PPT + kb;
      STAGE((kb + 3) & 3, (s + 3) & (NPHASE - 1));   // 6 outstanding now
      asm volatile("s_waitcnt vmcnt(4)" ::: "memory"); // buf (kb+1)&3 landed
      const char* nb = ldsW + ((kb + 1) & 3) * 2048;
      const i32x4 fn0 = *(const i32x4*)(nb + rdoff);         // next K-step's
      const i32x4 fn1 = *(const i32x4*)(nb + 1024 + rdoff);  // frags in flight
      __builtin_amdgcn_s_setprio(1);
      acc[0][0] = __builtin_amdgcn_mfma_i32_16x16x64_i8(areg[0][kb], fc0, acc[0][0], 0,0,0);
      acc[1][0] = __builtin_amdgcn_mfma_i32_16x16x64_i8(areg[1][kb], fc0, acc[1][0], 0,0,0);
      acc[2][0] = __builtin_amdgcn_mfma_i32_16x16x64_i8(areg[2][kb], fc0, acc[2][0], 0,0,0);
      acc[3][0] = __builtin_amdgcn_mfma_i32_16x16x64_i8(areg[3][kb], fc0, acc[3][0], 0,0,0);
      acc[0][1] = __builtin_amdgcn_mfma_i32_16x16x64_i8(areg[0][kb], fc1, acc[0][1], 0,0,0);
      acc[1][1] = __builtin_amdgcn_mfma_i32_16x16x64_i8(areg[1][kb], fc1, acc[1][1], 0,0,0);
      acc[2][1] = __builtin_amdgcn_mfma_i32_16x16x64_i8(areg[2][kb], fc1, acc[2][1], 0,0,0);
      acc[3][1] = __builtin_amdgcn_mfma_i32_16x16x64_i8(areg[3][kb], fc1, acc[3][1], 0,0,0);
      __builtin_amdgcn_s_setprio(0);
      fc0 = fn0; fc1 = fn1;
    }

    // ---- fused argmax over this 32-col tile: packed-key running max --------
    const int colb0 = t * NT;
    if (t == td || t == td + 1) {
      #pragma unroll
      for (int cf = 0; cf < 2; ++cf) {
        const float sc = sscl[colb0 + cf * 16 + (lane & 15)];
        const uint32_t code = 2047u - (uint32_t)(colb0 + cf * 16 + (lane & 15));
        const int gcol = colsplit + colb0 + cf * 16 + (lane & 15);
        #pragma unroll
        for (int rf = 0; rf < 4; ++rf) {
          #pragma unroll
          for (int r = 0; r < 4; ++r) {
            const int grow = rowbase + rf * 16 + (lane >> 4) * 4 + r;
            const float dv = fmaf((float)acc[rf][cf][r], sc, 4096.0f);
            uint32_t key = (__float_as_uint(dv) & 0xFFFFF800u) | code;
            if (gcol == grow) key = 0u;               // mask diagonal
            rkey[rf][r] = rkey[rf][r] > key ? rkey[rf][r] : key;
          }
        }
      }
    } else {
      #pragma unroll
      for (int cf = 0; cf < 2; ++cf) {
        const float sc = sscl[colb0 + cf * 16 + (lane & 15)];
        const uint32_t code = 2047u - (uint32_t)(colb0 + cf * 16 + (lane & 15));
        #pragma unroll
        for (int rf = 0; rf < 4; ++rf) {
          #pragma unroll
          for (int r = 0; r < 4; ++r) {
            const float dv = fmaf((float)acc[rf][cf][r], sc, 4096.0f);
            const uint32_t key = (__float_as_uint(dv) & 0xFFFFF800u) | code;
            rkey[rf][r] = rkey[rf][r] > key ? rkey[rf][r] : key;
          }
        }
      }
    }
  }

  // ---- cross-lane key max within each 16-lane group ------------------------
  #pragma unroll
  for (int m = 1; m <= 8; m <<= 1) {
    #pragma unroll
    for (int rf = 0; rf < 4; ++rf) {
      #pragma unroll
      for (int r = 0; r < 4; ++r) {
        const uint32_t ok =
            (uint32_t)__shfl_xor((int)rkey[rf][r], m, 64);
        rkey[rf][r] = rkey[rf][r] > ok ? rkey[rf][r] : ok;
      }
    }
  }
  if ((lane & 15) == 0) {
    #pragma unroll
    for (int rf = 0; rf < 4; ++rf) {
      #pragma unroll
      for (int r = 0; r < 4; ++r) {
        const int grow = rowbase + rf * 16 + (lane >> 4) * 4 + r;
        keys[cs * NROWS + grow] = rkey[rf][r];
      }
    }
  }
}

// ---------------- Kernel C1: combine splits, exact f32 distance + log -------
__global__ __launch_bounds__(256) void kdist(const float* __restrict__ in,
                                             const float* __restrict__ inv,
                                             const uint32_t* __restrict__ keys,
                                             float* __restrict__ partial) {
  __shared__ float acc4[4];
  const int lane = threadIdx.x & 63;
  const int wave = threadIdx.x >> 6;
  const int row = blockIdx.x * 4 + wave;
  uint32_t bk = 0u; int bs = 0;
  #pragma unroll
  for (int s = 0; s < CSPLIT; ++s) {
    const uint32_t k = keys[s * NROWS + row];
    if (k > bk) { bk = k; bs = s; }
  }
  const int bi = bs * COLS_PER_SPLIT + 2047 - (int)(bk & 2047u);
  const float ii = inv[row], jj = inv[bi];
  const float4* pi = (const float4*)(in + (size_t)row * DIM + lane * 8);
  const float4* pj = (const float4*)(in + (size_t)bi * DIM + lane * 8);
  const float4 a0 = pi[0], a1 = pi[1], b0 = pj[0], b1 = pj[1];
  float d, ss = 0.0f;
  d = a0.x*ii - b0.x*jj + 1e-8f; ss += d*d;
  d = a0.y*ii - b0.y*jj + 1e-8f; ss += d*d;
  d = a0.z*ii - b0.z*jj + 1e-8f; ss += d*d;
  d = a0.w*ii - b0.w*jj + 1e-8f; ss += d*d;
  d = a1.x*ii - b1.x*jj + 1e-8f; ss += d*d;
  d = a1.y*ii - b1.y*jj + 1e-8f; ss += d*d;
  d = a1.z*ii - b1.z*jj + 1e-8f; ss += d*d;
  d = a1.w*ii - b1.w*jj + 1e-8f; ss += d*d;
  #pragma unroll
  for (int m = 32; m >= 1; m >>= 1) ss += __shfl_xor(ss, m, 64);
  if (lane == 0) acc4[wave] = logf(sqrtf(ss) + 1e-8f);
  __syncthreads();
  if (threadIdx.x == 0)
    partial[blockIdx.x] = acc4[0] + acc4[1] + acc4[2] + acc4[3];
}

// ---------------- Kernel C2: final reduce -> loss ---------------------------
__global__ __launch_bounds__(256) void kfinal(const float* __restrict__ partial,
                                              float* __restrict__ out) {
  __shared__ float acc4[4];
  const int lane = threadIdx.x & 63;
  const int wave = threadIdx.x >> 6;
  float s = 0.0f;
  for (int i = threadIdx.x; i < NROWS / 4; i += 256) s += partial[i];
  #pragma unroll
  for (int m = 32; m >= 1; m >>= 1) s += __shfl_xor(s, m, 64);
  if (lane == 0) acc4[wave] = s;
  __syncthreads();
  if (threadIdx.x == 0)
    out[0] = -(acc4[0] + acc4[1] + acc4[2] + acc4[3]) * (1.0f / (float)NROWS);
}

extern "C" void kernel_launch(void* const* d_in, const int* in_sizes, int n_in,
                              void* d_out, int out_size, void* d_ws, size_t ws_size,
                              hipStream_t stream) {
  const float* in = (const float*)d_in[0];
  char* ws = (char*)d_ws;
  signed char* xq   = (signed char*)(ws);                  //  8,388,608 B
  float*       inv  = (float*)(ws + 8388608);              //     65,536 B
  float*       scl  = (float*)(ws + 8454144);              //     65,536 B
  uint32_t*    keys = (uint32_t*)(ws + 8519680);           //    524,288 B
  float*       part = (float*)(ws + 9043968);              //     16,384 B

  knorm<<<NROWS / 4, 256, 0, stream>>>(in, xq, inv, scl);
  kdots<<<(NROWS / BM) * CSPLIT, 256, 0, stream>>>(xq, scl, keys);
  kdist<<<NROWS / 4, 256, 0, stream>>>(in, inv, keys, part);
  kfinal<<<1, 256, 0, stream>>>(part, (float*)d_out);
}

// Round 9
// 163.877 us; speedup vs baseline: 1.6047x; 1.6047x over previous
//
#include <hip/hip_runtime.h>
#include <stdint.h>

#define NROWS 16384
#define DIM 512
#define CSPLIT 8
#define COLS_PER_SPLIT (NROWS / CSPLIT)   // 2048
#define BM 256                            // rows per block (4 waves x 64)
#define NT 64                             // cols per tile
#define BK 128                            // k per K-step
#define NTILES (COLS_PER_SPLIT / NT)      // 32
#define PPT (DIM / BK)                    // 4 K-steps per tile
#define NPHASE (NTILES * PPT)             // 128

using i32x4 = __attribute__((ext_vector_type(4))) int;
using char8 = __attribute__((ext_vector_type(8))) signed char;

#define AS1 __attribute__((address_space(1)))
#define AS3 __attribute__((address_space(3)))

// ---------------- Kernel A: L2-normalize + per-row i8 quantize --------------
__global__ __launch_bounds__(256) void knorm(const float* __restrict__ in,
                                             signed char* __restrict__ xq,
                                             float* __restrict__ inv,
                                             float* __restrict__ scl) {
  const int lane = threadIdx.x & 63;
  const int wave = threadIdx.x >> 6;
  const int row = blockIdx.x * 4 + wave;
  const float4* p = (const float4*)(in + (size_t)row * DIM + lane * 8);
  const float4 a = p[0], b = p[1];
  float ss = a.x*a.x + a.y*a.y + a.z*a.z + a.w*a.w
           + b.x*b.x + b.y*b.y + b.z*b.z + b.w*b.w;
  float am = fmaxf(fmaxf(fmaxf(fabsf(a.x), fabsf(a.y)), fmaxf(fabsf(a.z), fabsf(a.w))),
                   fmaxf(fmaxf(fabsf(b.x), fabsf(b.y)), fmaxf(fabsf(b.z), fabsf(b.w))));
  #pragma unroll
  for (int m = 32; m >= 1; m >>= 1) {
    ss += __shfl_xor(ss, m, 64);
    am = fmaxf(am, __shfl_xor(am, m, 64));
  }
  const float iv = 1.0f / fmaxf(sqrtf(ss), 1e-8f);
  const float r127 = 127.0f / am;
  char8 q;
  q[0] = (signed char)(int)rintf(a.x * r127);
  q[1] = (signed char)(int)rintf(a.y * r127);
  q[2] = (signed char)(int)rintf(a.z * r127);
  q[3] = (signed char)(int)rintf(a.w * r127);
  q[4] = (signed char)(int)rintf(b.x * r127);
  q[5] = (signed char)(int)rintf(b.y * r127);
  q[6] = (signed char)(int)rintf(b.z * r127);
  q[7] = (signed char)(int)rintf(b.w * r127);
  *(char8*)(xq + (size_t)row * DIM + lane * 8) = q;
  if (lane == 0) {
    inv[row] = iv;
    scl[row] = am * iv * (1.0f / 127.0f);
  }
}

// ---------------- Kernel B: i8 Gram + fused running argmax (packed keys) ----
// R6 structure: 4 waves x 64 rows, A register-resident, 4 x 8 KB LDS buffers,
// depth-3 prefetch, vmcnt(4) + ONE barrier per K-step, cluster-pipelined
// compiler-scheduled LDS reads, setprio around MFMA clusters.
// B tile layout [col][128B contig k] with both-sides XOR swizzle:
//  - STAGE reads 128B-contiguous row segments (16 lines/instr instead of 64)
//    with pre-swizzled global k-chunk (k16 ^ (col&7)), linear LDS dest.
//  - ds_read applies the same XOR; kk=1 offset is ro ^ 64 (XOR, not +64!).
__global__ __launch_bounds__(256, 2) void kdots(const signed char* __restrict__ xq,
                                                const float* __restrict__ scl,
                                                uint32_t* __restrict__ keys) {
  const int tid  = threadIdx.x;
  const int lane = tid & 63;
  const int wave = tid >> 6;
  const int bx = blockIdx.x;
  const int cs = bx & (CSPLIT - 1);     // same-cs blocks land on same XCD (%8)
  const int rb = bx >> 3;
  const int rowbase  = rb * BM + wave * 64;
  const int colsplit = cs * COLS_PER_SPLIT;
  // the one tile (per wave) containing diagonal elements, or -1
  const int tdiag = ((rowbase >> 11) == cs) ? ((rowbase - colsplit) >> 6) : -1;

  __shared__ signed char lds[4][NT * BK];   // 4 x 8 KB
  __shared__ float sscl[COLS_PER_SPLIT];    // 8 KB

  // stage this slice's column scales into LDS (read in epilogue only)
  {
    const float4* sp = (const float4*)(scl + colsplit + tid * 8);
    float4* dp = (float4*)(sscl + tid * 8);
    dp[0] = sp[0];
    dp[1] = sp[1];
  }

  // ---- A fragments in registers: 4 rowfrags x 8 kfrags(K=64) = 128 VGPR ----
  i32x4 areg[4][8];
  #pragma unroll
  for (int rf = 0; rf < 4; ++rf) {
    const signed char* ap =
        xq + (size_t)(rowbase + rf * 16 + (lane & 15)) * DIM + ((lane >> 4) * 16);
    #pragma unroll
    for (int kf = 0; kf < 8; ++kf)
      areg[rf][kf] = *(const i32x4*)(ap + kf * 64);
  }

  uint32_t rkey[4][4];
  #pragma unroll
  for (int rf = 0; rf < 4; ++rf)
    #pragma unroll
    for (int r = 0; r < 4; ++r) rkey[rf][r] = 0u;

  // stage one 8 KB buffer: 2 global_load_lds(16B) per thread.
  // u -> col = u>>3 (0..63), k16 = u&7; LDS dest linear u*16 = [col][k16*16];
  // global source k-chunk = k16 ^ (col&7)  (inverse-swizzled source, rule 21).
  // Lanes u&7==0..7 of one col read ONE 128B-contig, 128B-aligned segment.
  auto STAGE = [&](int buf, int p) {
    const int tt = p >> 2, kb2 = p & 3;
    #pragma unroll
    for (int h = 0; h < 2; ++h) {
      const int u = h * 256 + tid;
      const int col = u >> 3;
      const int k16 = u & 7;
      const signed char* g = xq + (size_t)(colsplit + tt * NT + col) * DIM
                           + kb2 * BK + ((k16 ^ (col & 7)) << 4);
      char* l = ((char*)&lds[buf][0]) + u * 16;
      __builtin_amdgcn_global_load_lds((AS1 const void*)g, (AS3 void*)l, 16, 0, 0);
    }
  };

  __syncthreads();   // sscl visible; drains all prior vmem (vmcnt -> 0)
  STAGE(0, 0); STAGE(1, 1); STAGE(2, 2);   // depth-3 prologue: 6 outstanding

  // ds_read byte offset for (cf,kk): cf*2048 + c15*128 + ((kk*4+hi)^s)*16,
  // c15=lane&15, hi=lane>>4, s=c15&7.  kk=0 -> ro0; kk=1 -> ro0 ^ 64 (XOR:
  // (4+hi)^s = (hi^s)^4 since hi<4; the carry-free bit-6 toggle).
  const int ro0 = (lane & 15) * 128 + (((lane >> 4) ^ (lane & 7)) << 4);
  const int ro1 = ro0 ^ 64;

#define CLUSTER(Q, BA, BB)                                                     \
  __builtin_amdgcn_s_setprio(1);                                              \
  acc[0][Q] = __builtin_amdgcn_mfma_i32_16x16x64_i8(a0, BA, acc[0][Q], 0,0,0);\
  acc[1][Q] = __builtin_amdgcn_mfma_i32_16x16x64_i8(a1, BA, acc[1][Q], 0,0,0);\
  acc[2][Q] = __builtin_amdgcn_mfma_i32_16x16x64_i8(a2, BA, acc[2][Q], 0,0,0);\
  acc[3][Q] = __builtin_amdgcn_mfma_i32_16x16x64_i8(a3, BA, acc[3][Q], 0,0,0);\
  acc[0][Q] = __builtin_amdgcn_mfma_i32_16x16x64_i8(a4, BB, acc[0][Q], 0,0,0);\
  acc[1][Q] = __builtin_amdgcn_mfma_i32_16x16x64_i8(a5, BB, acc[1][Q], 0,0,0);\
  acc[2][Q] = __builtin_amdgcn_mfma_i32_16x16x64_i8(a6, BB, acc[2][Q], 0,0,0);\
  acc[3][Q] = __builtin_amdgcn_mfma_i32_16x16x64_i8(a7, BB, acc[3][Q], 0,0,0);\
  __builtin_amdgcn_s_setprio(0);

  for (int t = 0; t < NTILES; ++t) {
    i32x4 acc[4][4];
    #pragma unroll
    for (int rf = 0; rf < 4; ++rf)
      #pragma unroll
      for (int cf = 0; cf < 4; ++cf) acc[rf][cf] = (i32x4){0, 0, 0, 0};

    #pragma unroll
    for (int kb = 0; kb < PPT; ++kb) {
      // buffer for this K-step = (t*4+kb)&3 = kb&3 (compile-time per kb)
      asm volatile("s_waitcnt vmcnt(4)" ::: "memory"); // this buf's loads in
      __builtin_amdgcn_s_barrier();                    // ...across ALL waves;
      asm volatile("" ::: "memory");                   // prev buf fully read
      STAGE((kb + 3) & 3, (t * PPT + kb + 3) & (NPHASE - 1)); // depth-3
      const char* base = (const char*)&lds[kb & 3][0];
      const i32x4 a0 = areg[0][kb*2],   a1 = areg[1][kb*2];
      const i32x4 a2 = areg[2][kb*2],   a3 = areg[3][kb*2];
      const i32x4 a4 = areg[0][kb*2+1], a5 = areg[1][kb*2+1];
      const i32x4 a6 = areg[2][kb*2+1], a7 = areg[3][kb*2+1];
      i32x4 b0a = *(const i32x4*)(base + ro0);          // q0 kk0
      i32x4 b0b = *(const i32x4*)(base + ro1);          // q0 kk1
      i32x4 b1a = *(const i32x4*)(base + 2048 + ro0);   // q1 in flight
      i32x4 b1b = *(const i32x4*)(base + 2048 + ro1);
      CLUSTER(0, b0a, b0b)
      b0a = *(const i32x4*)(base + 4096 + ro0);         // q2 in flight
      b0b = *(const i32x4*)(base + 4096 + ro1);
      CLUSTER(1, b1a, b1b)
      b1a = *(const i32x4*)(base + 6144 + ro0);         // q3 in flight
      b1b = *(const i32x4*)(base + 6144 + ro1);
      CLUSTER(2, b0a, b0b)
      CLUSTER(3, b1a, b1b)
    }

    // ---- fused argmax over this 64-col tile: packed-key running max --------
    const int colb0 = t * NT;
    if (t == tdiag) {
      #pragma unroll
      for (int cf = 0; cf < 4; ++cf) {
        const float sc = sscl[colb0 + cf * 16 + (lane & 15)];
        const uint32_t code = 2047u - (uint32_t)(colb0 + cf * 16 + (lane & 15));
        const int gcol = colsplit + colb0 + cf * 16 + (lane & 15);
        #pragma unroll
        for (int rf = 0; rf < 4; ++rf) {
          #pragma unroll
          for (int r = 0; r < 4; ++r) {
            const int grow = rowbase + rf * 16 + (lane >> 4) * 4 + r;
            const float dv = fmaf((float)acc[rf][cf][r], sc, 4096.0f);
            uint32_t key = (__float_as_uint(dv) & 0xFFFFF800u) | code;
            if (gcol == grow) key = 0u;               // mask diagonal
            rkey[rf][r] = rkey[rf][r] > key ? rkey[rf][r] : key;
          }
        }
      }
    } else {
      #pragma unroll
      for (int cf = 0; cf < 4; ++cf) {
        const float sc = sscl[colb0 + cf * 16 + (lane & 15)];
        const uint32_t code = 2047u - (uint32_t)(colb0 + cf * 16 + (lane & 15));
        #pragma unroll
        for (int rf = 0; rf < 4; ++rf) {
          #pragma unroll
          for (int r = 0; r < 4; ++r) {
            const float dv = fmaf((float)acc[rf][cf][r], sc, 4096.0f);
            const uint32_t key = (__float_as_uint(dv) & 0xFFFFF800u) | code;
            rkey[rf][r] = rkey[rf][r] > key ? rkey[rf][r] : key;
          }
        }
      }
    }
  }
#undef CLUSTER

  // ---- cross-lane key max within each 16-lane group ------------------------
  #pragma unroll
  for (int m = 1; m <= 8; m <<= 1) {
    #pragma unroll
    for (int rf = 0; rf < 4; ++rf) {
      #pragma unroll
      for (int r = 0; r < 4; ++r) {
        const uint32_t ok =
            (uint32_t)__shfl_xor((int)rkey[rf][r], m, 64);
        rkey[rf][r] = rkey[rf][r] > ok ? rkey[rf][r] : ok;
      }
    }
  }
  if ((lane & 15) == 0) {
    #pragma unroll
    for (int rf = 0; rf < 4; ++rf) {
      #pragma unroll
      for (int r = 0; r < 4; ++r) {
        const int grow = rowbase + rf * 16 + (lane >> 4) * 4 + r;
        keys[cs * NROWS + grow] = rkey[rf][r];
      }
    }
  }
}

// ---------------- Kernel C1: combine splits, exact f32 distance + log -------
__global__ __launch_bounds__(256) void kdist(const float* __restrict__ in,
                                             const float* __restrict__ inv,
                                             const uint32_t* __restrict__ keys,
                                             float* __restrict__ partial) {
  __shared__ float acc4[4];
  const int lane = threadIdx.x & 63;
  const int wave = threadIdx.x >> 6;
  const int row = blockIdx.x * 4 + wave;
  uint32_t bk = 0u; int bs = 0;
  #pragma unroll
  for (int s = 0; s < CSPLIT; ++s) {
    const uint32_t k = keys[s * NROWS + row];
    if (k > bk) { bk = k; bs = s; }
  }
  const int bi = bs * COLS_PER_SPLIT + 2047 - (int)(bk & 2047u);
  const float ii = inv[row], jj = inv[bi];
  const float4* pi = (const float4*)(in + (size_t)row * DIM + lane * 8);
  const float4* pj = (const float4*)(in + (size_t)bi * DIM + lane * 8);
  const float4 a0 = pi[0], a1 = pi[1], b0 = pj[0], b1 = pj[1];
  float d, ss = 0.0f;
  d = a0.x*ii - b0.x*jj + 1e-8f; ss += d*d;
  d = a0.y*ii - b0.y*jj + 1e-8f; ss += d*d;
  d = a0.z*ii - b0.z*jj + 1e-8f; ss += d*d;
  d = a0.w*ii - b0.w*jj + 1e-8f; ss += d*d;
  d = a1.x*ii - b1.x*jj + 1e-8f; ss += d*d;
  d = a1.y*ii - b1.y*jj + 1e-8f; ss += d*d;
  d = a1.z*ii - b1.z*jj + 1e-8f; ss += d*d;
  d = a1.w*ii - b1.w*jj + 1e-8f; ss += d*d;
  #pragma unroll
  for (int m = 32; m >= 1; m >>= 1) ss += __shfl_xor(ss, m, 64);
  if (lane == 0) acc4[wave] = logf(sqrtf(ss) + 1e-8f);
  __syncthreads();
  if (threadIdx.x == 0)
    partial[blockIdx.x] = acc4[0] + acc4[1] + acc4[2] + acc4[3];
}

// ---------------- Kernel C2: final reduce -> loss ---------------------------
__global__ __launch_bounds__(256) void kfinal(const float* __restrict__ partial,
                                              float* __restrict__ out) {
  __shared__ float acc4[4];
  const int lane = threadIdx.x & 63;
  const int wave = threadIdx.x >> 6;
  float s = 0.0f;
  for (int i = threadIdx.x; i < NROWS / 4; i += 256) s += partial[i];
  #pragma unroll
  for (int m = 32; m >= 1; m >>= 1) s += __shfl_xor(s, m, 64);
  if (lane == 0) acc4[wave] = s;
  __syncthreads();
  if (threadIdx.x == 0)
    out[0] = -(acc4[0] + acc4[1] + acc4[2] + acc4[3]) * (1.0f / (float)NROWS);
}

extern "C" void kernel_launch(void* const* d_in, const int* in_sizes, int n_in,
                              void* d_out, int out_size, void* d_ws, size_t ws_size,
                              hipStream_t stream) {
  const float* in = (const float*)d_in[0];
  char* ws = (char*)d_ws;
  signed char* xq   = (signed char*)(ws);                  //  8,388,608 B
  float*       inv  = (float*)(ws + 8388608);              //     65,536 B
  float*       scl  = (float*)(ws + 8454144);              //     65,536 B
  uint32_t*    keys = (uint32_t*)(ws + 8519680);           //    524,288 B
  float*       part = (float*)(ws + 9043968);              //     16,384 B

  knorm<<<NROWS / 4, 256, 0, stream>>>(in, xq, inv, scl);
  kdots<<<(NROWS / BM) * CSPLIT, 256, 0, stream>>>(xq, scl, keys);
  kdist<<<NROWS / 4, 256, 0, stream>>>(in, inv, keys, part);
  kfinal<<<1, 256, 0, stream>>>(part, (float*)d_out);
}

// Round 10
// 137.424 us; speedup vs baseline: 1.9136x; 1.1925x over previous
//
#include <hip/hip_runtime.h>
#include <stdint.h>

#define NROWS 16384
#define DIM 512
#define CSPLIT 8
#define COLS_PER_SPLIT (NROWS / CSPLIT)   // 2048
#define BM 256                            // rows per block (4 waves x 64)
#define NT 64                             // cols per tile
#define BK 128                            // k per K-step
#define NTILES (COLS_PER_SPLIT / NT)      // 32
#define PPT (DIM / BK)                    // 4 K-steps per tile
#define NPHASE (NTILES * PPT)             // 128

using i32x4 = __attribute__((ext_vector_type(4))) int;
using char8 = __attribute__((ext_vector_type(8))) signed char;

#define AS1 __attribute__((address_space(1)))
#define AS3 __attribute__((address_space(3)))

// ---------------- Kernel A: L2-normalize + FIXED-scale i8 quantize ----------
// q = round(clamp(x_norm * 508, -127, 127));  508 = 127/0.25.  The global
// scale is constant, so argmax over columns reduces to integer argmax of idot.
__global__ __launch_bounds__(256) void knorm(const float* __restrict__ in,
                                             signed char* __restrict__ xq,
                                             float* __restrict__ inv) {
  const int lane = threadIdx.x & 63;
  const int wave = threadIdx.x >> 6;
  const int row = blockIdx.x * 4 + wave;
  const float4* p = (const float4*)(in + (size_t)row * DIM + lane * 8);
  const float4 a = p[0], b = p[1];
  float ss = a.x*a.x + a.y*a.y + a.z*a.z + a.w*a.w
           + b.x*b.x + b.y*b.y + b.z*b.z + b.w*b.w;
  #pragma unroll
  for (int m = 32; m >= 1; m >>= 1) ss += __shfl_xor(ss, m, 64);
  const float iv = 1.0f / fmaxf(sqrtf(ss), 1e-8f);
  const float s508 = iv * 508.0f;
  char8 q;
  q[0] = (signed char)(int)rintf(fminf(fmaxf(a.x * s508, -127.f), 127.f));
  q[1] = (signed char)(int)rintf(fminf(fmaxf(a.y * s508, -127.f), 127.f));
  q[2] = (signed char)(int)rintf(fminf(fmaxf(a.z * s508, -127.f), 127.f));
  q[3] = (signed char)(int)rintf(fminf(fmaxf(a.w * s508, -127.f), 127.f));
  q[4] = (signed char)(int)rintf(fminf(fmaxf(b.x * s508, -127.f), 127.f));
  q[5] = (signed char)(int)rintf(fminf(fmaxf(b.y * s508, -127.f), 127.f));
  q[6] = (signed char)(int)rintf(fminf(fmaxf(b.z * s508, -127.f), 127.f));
  q[7] = (signed char)(int)rintf(fminf(fmaxf(b.w * s508, -127.f), 127.f));
  *(char8*)(xq + (size_t)row * DIM + lane * 8) = q;
  if (lane == 0) inv[row] = iv;
}

// ---------------- Kernel B: i8 Gram + fused integer argmax ------------------
// R9 structure + (1) integer packed keys (3 VALU/value: ashr, lshl_add, max),
// (2) zero-C first K-step (no acc init), (3) prev-tile epilogue interleaved
// into kb=0's clusters so its VALU hides under MFMA + ds latency.
__global__ __launch_bounds__(256, 2) void kdots(const signed char* __restrict__ xq,
                                                uint32_t* __restrict__ keys) {
  const int tid  = threadIdx.x;
  const int lane = tid & 63;
  const int wave = tid >> 6;
  const int bx = blockIdx.x;
  const int cs = bx & (CSPLIT - 1);     // same-cs blocks land on same XCD (%8)
  const int rb = bx >> 3;
  const int rowbase  = rb * BM + wave * 64;
  const int colsplit = cs * COLS_PER_SPLIT;
  // the one tile (per wave) containing diagonal elements, or -1
  const int tdiag = ((rowbase >> 11) == cs) ? ((rowbase - colsplit) >> 6) : -1;
  const int c15 = lane & 15;
  const int hi4 = (lane >> 4) * 4;

  __shared__ signed char lds[4][NT * BK];   // 4 x 8 KB

  // ---- A fragments in registers: 4 rowfrags x 8 kfrags(K=64) = 128 VGPR ----
  i32x4 areg[4][8];
  #pragma unroll
  for (int rf = 0; rf < 4; ++rf) {
    const signed char* ap =
        xq + (size_t)(rowbase + rf * 16 + c15) * DIM + ((lane >> 4) * 16);
    #pragma unroll
    for (int kf = 0; kf < 8; ++kf)
      areg[rf][kf] = *(const i32x4*)(ap + kf * 64);
  }

  uint32_t rkey[4][4];
  #pragma unroll
  for (int rf = 0; rf < 4; ++rf)
    #pragma unroll
    for (int r = 0; r < 4; ++r) rkey[rf][r] = 0u;

  i32x4 acc[4][4];   // written by zero-C clusters each tile; read next tile

  // stage one 8 KB buffer: 2 global_load_lds(16B) per thread.
  // LDS layout [col][8 x 16B k-chunks], source k-chunk pre-swizzled k16^(col&7).
  auto STAGE = [&](int buf, int p) {
    const int tt = p >> 2, kb2 = p & 3;
    #pragma unroll
    for (int h = 0; h < 2; ++h) {
      const int u = h * 256 + tid;
      const int col = u >> 3;
      const int k16 = u & 7;
      const signed char* g = xq + (size_t)(colsplit + tt * NT + col) * DIM
                           + kb2 * BK + ((k16 ^ (col & 7)) << 4);
      char* l = ((char*)&lds[buf][0]) + u * 16;
      __builtin_amdgcn_global_load_lds((AS1 const void*)g, (AS3 void*)l, 16, 0, 0);
    }
  };

  __syncthreads();   // drains areg loads (vmcnt -> 0)
  STAGE(0, 0); STAGE(1, 1); STAGE(2, 2);   // depth-3 prologue: 6 outstanding

  // ds_read offsets: cf*2048 + c15*128 + ((kk*4+hi)^(c15&7))*16; kk=1 = ^64
  const int ro0 = c15 * 128 + (((lane >> 4) ^ (lane & 7)) << 4);
  const int ro1 = ro0 ^ 64;

// integer packed-key epilogue chunk for prev tile's acc[*][Q] (Q literal)
#define EPI(Q, COLB0P, DG)                                                     \
  do {                                                                         \
    const uint32_t k0c =                                                       \
        0x80000000u + 2047u - (uint32_t)((COLB0P) + (Q) * 16 + c15);           \
    _Pragma("unroll")                                                          \
    for (int rf = 0; rf < 4; ++rf) {                                           \
      _Pragma("unroll")                                                        \
      for (int r = 0; r < 4; ++r) {                                            \
        const int t1 = acc[rf][Q][r] >> 3;                                     \
        uint32_t key = ((uint32_t)t1 << 11) + k0c;                             \
        if (rf == (Q) && (DG)) key = (c15 == hi4 + r) ? 0u : key;              \
        rkey[rf][r] = rkey[rf][r] > key ? rkey[rf][r] : key;                   \
      }                                                                        \
    }                                                                          \
  } while (0)

#define CLUSTER(Q, BA, BB)                                                     \
  __builtin_amdgcn_s_setprio(1);                                              \
  acc[0][Q] = __builtin_amdgcn_mfma_i32_16x16x64_i8(a0, BA, acc[0][Q], 0,0,0);\
  acc[1][Q] = __builtin_amdgcn_mfma_i32_16x16x64_i8(a1, BA, acc[1][Q], 0,0,0);\
  acc[2][Q] = __builtin_amdgcn_mfma_i32_16x16x64_i8(a2, BA, acc[2][Q], 0,0,0);\
  acc[3][Q] = __builtin_amdgcn_mfma_i32_16x16x64_i8(a3, BA, acc[3][Q], 0,0,0);\
  acc[0][Q] = __builtin_amdgcn_mfma_i32_16x16x64_i8(a4, BB, acc[0][Q], 0,0,0);\
  acc[1][Q] = __builtin_amdgcn_mfma_i32_16x16x64_i8(a5, BB, acc[1][Q], 0,0,0);\
  acc[2][Q] = __builtin_amdgcn_mfma_i32_16x16x64_i8(a6, BB, acc[2][Q], 0,0,0);\
  acc[3][Q] = __builtin_amdgcn_mfma_i32_16x16x64_i8(a7, BB, acc[3][Q], 0,0,0);\
  __builtin_amdgcn_s_setprio(0);

#define CLUSTERZ(Q, BA, BB)                                                    \
  __builtin_amdgcn_s_setprio(1);                                              \
  acc[0][Q] = __builtin_amdgcn_mfma_i32_16x16x64_i8(a0, BA, (i32x4){0,0,0,0}, 0,0,0);\
  acc[1][Q] = __builtin_amdgcn_mfma_i32_16x16x64_i8(a1, BA, (i32x4){0,0,0,0}, 0,0,0);\
  acc[2][Q] = __builtin_amdgcn_mfma_i32_16x16x64_i8(a2, BA, (i32x4){0,0,0,0}, 0,0,0);\
  acc[3][Q] = __builtin_amdgcn_mfma_i32_16x16x64_i8(a3, BA, (i32x4){0,0,0,0}, 0,0,0);\
  acc[0][Q] = __builtin_amdgcn_mfma_i32_16x16x64_i8(a4, BB, acc[0][Q], 0,0,0);\
  acc[1][Q] = __builtin_amdgcn_mfma_i32_16x16x64_i8(a5, BB, acc[1][Q], 0,0,0);\
  acc[2][Q] = __builtin_amdgcn_mfma_i32_16x16x64_i8(a6, BB, acc[2][Q], 0,0,0);\
  acc[3][Q] = __builtin_amdgcn_mfma_i32_16x16x64_i8(a7, BB, acc[3][Q], 0,0,0);\
  __builtin_amdgcn_s_setprio(0);

  for (int t = 0; t < NTILES; ++t) {
    const int colb0p = (t - 1) * NT;
    const bool dg = ((t - 1) == tdiag);
    // ---- K-step kb=0: zero-C clusters + interleaved prev-tile epilogue ----
    asm volatile("s_waitcnt vmcnt(4)" ::: "memory");
    __builtin_amdgcn_s_barrier();
    asm volatile("" ::: "memory");
    STAGE(3, (t * PPT + 3) & (NPHASE - 1));
    {
      const char* base = (const char*)&lds[0][0];
      const i32x4 a0 = areg[0][0], a1 = areg[1][0];
      const i32x4 a2 = areg[2][0], a3 = areg[3][0];
      const i32x4 a4 = areg[0][1], a5 = areg[1][1];
      const i32x4 a6 = areg[2][1], a7 = areg[3][1];
      i32x4 b0a = *(const i32x4*)(base + ro0);
      i32x4 b0b = *(const i32x4*)(base + ro1);
      i32x4 b1a = *(const i32x4*)(base + 2048 + ro0);
      i32x4 b1b = *(const i32x4*)(base + 2048 + ro1);
      if (t) EPI(0, colb0p, dg);
      CLUSTERZ(0, b0a, b0b)
      b0a = *(const i32x4*)(base + 4096 + ro0);
      b0b = *(const i32x4*)(base + 4096 + ro1);
      if (t) EPI(1, colb0p, dg);
      CLUSTERZ(1, b1a, b1b)
      b1a = *(const i32x4*)(base + 6144 + ro0);
      b1b = *(const i32x4*)(base + 6144 + ro1);
      if (t) EPI(2, colb0p, dg);
      CLUSTERZ(2, b0a, b0b)
      if (t) EPI(3, colb0p, dg);
      CLUSTERZ(3, b1a, b1b)
    }
    // ---- K-steps kb=1..3: accumulating clusters ----
    #pragma unroll
    for (int kb = 1; kb < PPT; ++kb) {
      asm volatile("s_waitcnt vmcnt(4)" ::: "memory");
      __builtin_amdgcn_s_barrier();
      asm volatile("" ::: "memory");
      STAGE((kb + 3) & 3, (t * PPT + kb + 3) & (NPHASE - 1));
      const char* base = (const char*)&lds[kb & 3][0];
      const i32x4 a0 = areg[0][kb*2],   a1 = areg[1][kb*2];
      const i32x4 a2 = areg[2][kb*2],   a3 = areg[3][kb*2];
      const i32x4 a4 = areg[0][kb*2+1], a5 = areg[1][kb*2+1];
      const i32x4 a6 = areg[2][kb*2+1], a7 = areg[3][kb*2+1];
      i32x4 b0a = *(const i32x4*)(base + ro0);
      i32x4 b0b = *(const i32x4*)(base + ro1);
      i32x4 b1a = *(const i32x4*)(base + 2048 + ro0);
      i32x4 b1b = *(const i32x4*)(base + 2048 + ro1);
      CLUSTER(0, b0a, b0b)
      b0a = *(const i32x4*)(base + 4096 + ro0);
      b0b = *(const i32x4*)(base + 4096 + ro1);
      CLUSTER(1, b1a, b1b)
      b1a = *(const i32x4*)(base + 6144 + ro0);
      b1b = *(const i32x4*)(base + 6144 + ro1);
      CLUSTER(2, b0a, b0b)
      CLUSTER(3, b1a, b1b)
    }
  }
  // ---- final epilogue for tile NTILES-1 ----
  {
    const int colb0p = (NTILES - 1) * NT;
    const bool dg = ((NTILES - 1) == tdiag);
    EPI(0, colb0p, dg);
    EPI(1, colb0p, dg);
    EPI(2, colb0p, dg);
    EPI(3, colb0p, dg);
  }
#undef CLUSTER
#undef CLUSTERZ
#undef EPI

  // ---- cross-lane key max within each 16-lane group ------------------------
  #pragma unroll
  for (int m = 1; m <= 8; m <<= 1) {
    #pragma unroll
    for (int rf = 0; rf < 4; ++rf) {
      #pragma unroll
      for (int r = 0; r < 4; ++r) {
        const uint32_t ok =
            (uint32_t)__shfl_xor((int)rkey[rf][r], m, 64);
        rkey[rf][r] = rkey[rf][r] > ok ? rkey[rf][r] : ok;
      }
    }
  }
  if (c15 == 0) {
    #pragma unroll
    for (int rf = 0; rf < 4; ++rf) {
      #pragma unroll
      for (int r = 0; r < 4; ++r) {
        const int grow = rowbase + rf * 16 + hi4 + r;
        keys[cs * NROWS + grow] = rkey[rf][r];
      }
    }
  }
}

// ---------------- Kernel C1: combine splits, exact f32 distance + log -------
__global__ __launch_bounds__(256) void kdist(const float* __restrict__ in,
                                             const float* __restrict__ inv,
                                             const uint32_t* __restrict__ keys,
                                             float* __restrict__ partial) {
  __shared__ float acc4[4];
  const int lane = threadIdx.x & 63;
  const int wave = threadIdx.x >> 6;
  const int row = blockIdx.x * 4 + wave;
  uint32_t bk = 0u; int bs = 0;
  #pragma unroll
  for (int s = 0; s < CSPLIT; ++s) {
    const uint32_t k = keys[s * NROWS + row];
    if (k > bk) { bk = k; bs = s; }
  }
  const int bi = bs * COLS_PER_SPLIT + 2047 - (int)(bk & 2047u);
  const float ii = inv[row], jj = inv[bi];
  const float4* pi = (const float4*)(in + (size_t)row * DIM + lane * 8);
  const float4* pj = (const float4*)(in + (size_t)bi * DIM + lane * 8);
  const float4 a0 = pi[0], a1 = pi[1], b0 = pj[0], b1 = pj[1];
  float d, ss = 0.0f;
  d = a0.x*ii - b0.x*jj + 1e-8f; ss += d*d;
  d = a0.y*ii - b0.y*jj + 1e-8f; ss += d*d;
  d = a0.z*ii - b0.z*jj + 1e-8f; ss += d*d;
  d = a0.w*ii - b0.w*jj + 1e-8f; ss += d*d;
  d = a1.x*ii - b1.x*jj + 1e-8f; ss += d*d;
  d = a1.y*ii - b1.y*jj + 1e-8f; ss += d*d;
  d = a1.z*ii - b1.z*jj + 1e-8f; ss += d*d;
  d = a1.w*ii - b1.w*jj + 1e-8f; ss += d*d;
  #pragma unroll
  for (int m = 32; m >= 1; m >>= 1) ss += __shfl_xor(ss, m, 64);
  if (lane == 0) acc4[wave] = logf(sqrtf(ss) + 1e-8f);
  __syncthreads();
  if (threadIdx.x == 0)
    partial[blockIdx.x] = acc4[0] + acc4[1] + acc4[2] + acc4[3];
}

// ---------------- Kernel C2: final reduce -> loss ---------------------------
__global__ __launch_bounds__(256) void kfinal(const float* __restrict__ partial,
                                              float* __restrict__ out) {
  __shared__ float acc4[4];
  const int lane = threadIdx.x & 63;
  const int wave = threadIdx.x >> 6;
  float s = 0.0f;
  for (int i = threadIdx.x; i < NROWS / 4; i += 256) s += partial[i];
  #pragma unroll
  for (int m = 32; m >= 1; m >>= 1) s += __shfl_xor(s, m, 64);
  if (lane == 0) acc4[wave] = s;
  __syncthreads();
  if (threadIdx.x == 0)
    out[0] = -(acc4[0] + acc4[1] + acc4[2] + acc4[3]) * (1.0f / (float)NROWS);
}

extern "C" void kernel_launch(void* const* d_in, const int* in_sizes, int n_in,
                              void* d_out, int out_size, void* d_ws, size_t ws_size,
                              hipStream_t stream) {
  const float* in = (const float*)d_in[0];
  char* ws = (char*)d_ws;
  signed char* xq   = (signed char*)(ws);                  //  8,388,608 B
  float*       inv  = (float*)(ws + 8388608);              //     65,536 B
  uint32_t*    keys = (uint32_t*)(ws + 8454144);           //    524,288 B
  float*       part = (float*)(ws + 8978432);              //     16,384 B

  knorm<<<NROWS / 4, 256, 0, stream>>>(in, xq, inv);
  kdots<<<(NROWS / BM) * CSPLIT, 256, 0, stream>>>(xq, keys);
  kdist<<<NROWS / 4, 256, 0, stream>>>(in, inv, keys, part);
  kfinal<<<1, 256, 0, stream>>>(part, (float*)d_out);
}